// Round 16
// baseline (414.892 us; speedup 1.0000x reference)
//
#include <hip/hip_runtime.h>
#include <hip/hip_bf16.h>

#define NN 200000
#define NE 600000
#define CH 256
#define NBLK_SCAN 196   // ceil(200000/1024)

typedef short bf16x8 __attribute__((ext_vector_type(8)));
typedef float f32x4 __attribute__((ext_vector_type(4)));
typedef unsigned short ushort8v __attribute__((ext_vector_type(8)));

__device__ __forceinline__ unsigned short f2bf(float f) {
    unsigned int u = __builtin_bit_cast(unsigned int, f);
    u = (u + 0x7FFFu + ((u >> 16) & 1u)) >> 16;
    return (unsigned short)u;
}
__device__ __forceinline__ float bf2f(unsigned short u) {
    unsigned int v = ((unsigned int)u) << 16;
    return __builtin_bit_cast(float, v);
}

// Wt[j][k] = bf16(W[k][j])
__global__ void k_wt(const float* __restrict__ W, unsigned short* __restrict__ Wt) {
    int j = blockIdx.x, k = threadIdx.x;
    Wt[j * CH + k] = f2bf(W[k * CH + j]);
}

// prep for fallback path: Wt + degree count
__global__ __launch_bounds__(256) void k_prep(const float* __restrict__ W,
                                              unsigned short* __restrict__ Wt,
                                              const int* __restrict__ te,
                                              int* __restrict__ deg) {
    const int t = blockIdx.x * 256 + threadIdx.x;
    const int S = gridDim.x * 256;
    for (int e = t; e < NE; e += S) atomicAdd(&deg[te[e]], 1);
    for (int i = t; i < CH * CH; i += S) {
        int j = i >> 8, k = i & 255;
        Wt[j * CH + k] = f2bf(W[k * CH + j]);
    }
}

__global__ __launch_bounds__(256) void k_scanA(const int* __restrict__ deg,
                                               int* __restrict__ off,
                                               int* __restrict__ bsum) {
    __shared__ int ts[256];
    int tid = threadIdx.x;
    int base = blockIdx.x * 1024 + tid * 4;
    int v[4];
#pragma unroll
    for (int j = 0; j < 4; ++j) {
        int idx = base + j;
        v[j] = (idx < NN) ? deg[idx] : 0;
    }
    int tsum = v[0] + v[1] + v[2] + v[3];
    ts[tid] = tsum;
    __syncthreads();
    int x = tsum;
    for (int ofs = 1; ofs < 256; ofs <<= 1) {
        int y = (tid >= ofs) ? ts[tid - ofs] : 0;
        __syncthreads();
        x += y;
        ts[tid] = x;
        __syncthreads();
    }
    int run = x - tsum;
#pragma unroll
    for (int j = 0; j < 4; ++j) {
        int idx = base + j;
        if (idx < NN) off[idx] = run;
        run += v[j];
    }
    if (tid == 255) bsum[blockIdx.x] = x;
}

// scanC: every block locally scans the 196 block sums, applies its prefix
__global__ __launch_bounds__(256) void k_scanC(int* __restrict__ off,
                                               const int* __restrict__ bsum,
                                               int* __restrict__ cur) {
    __shared__ int ts[256];
    int tid = threadIdx.x;
    int v = (tid < NBLK_SCAN) ? bsum[tid] : 0;
    ts[tid] = v;
    __syncthreads();
    int x = v;
    for (int ofs = 1; ofs < 256; ofs <<= 1) {
        int y = (tid >= ofs) ? ts[tid - ofs] : 0;
        __syncthreads();
        x += y;
        ts[tid] = x;
        __syncthreads();
    }
    const int bo = (blockIdx.x == 0) ? 0 : ts[blockIdx.x - 1];
    int base = blockIdx.x * 1024 + tid * 4;
#pragma unroll
    for (int j = 0; j < 4; ++j) {
        int idx = base + j;
        if (idx < NN) {
            int o = off[idx] + bo;
            off[idx] = o;
            cur[idx] = o;
        }
    }
}

__global__ void k_fill(const int* __restrict__ se, const int* __restrict__ te,
                       int* __restrict__ cur, int* __restrict__ elist) {
    int e = blockIdx.x * 256 + threadIdx.x;
    if (e < NE) {
        int t = te[e];
        int pos = atomicAdd(&cur[t], 1);
        elist[pos] = se[e];
    }
}

// ---------------- Path A ----------------
// K1: Z = x @ W (bf16 out). Barrier-free, LDS-free: each wave owns a 16-row
// x 256-col tile. A-fragments load DIRECTLY from global x (16x16x32 A-layout
// row=lane&15, k=8q+j -> two contiguous float4 per k-step); all 16 issued
// up-front and pinned live (asm keep-alive). B streams from L2-resident Wt.
// Latency hidden purely by TLP (12 waves/CU). Fused single-shot degree count.
__global__ __launch_bounds__(256, 3) void k_zw(const float* __restrict__ x,
                                               const unsigned short* __restrict__ Wt,
                                               unsigned short* __restrict__ zbf,
                                               const int* __restrict__ te,
                                               int* __restrict__ deg) {
    const int tid = threadIdx.x;
    const int wid = tid >> 6;
    const int lane = tid & 63;
    const int r16 = lane & 15;
    const int q = lane >> 4;

    // fused degree count (single shot: 3125*256 = 800000 >= NE)
    {
        const int e = blockIdx.x * 256 + tid;
        if (e < NE) atomicAdd(&deg[te[e]], 1);
    }

    const int rb = blockIdx.x * 64 + wid * 16;   // 3125 blocks * 64 rows
    const float* arow = x + (size_t)(rb + r16) * CH + q * 8;

    // prefetch the wave's entire A-slice: 16 independent float4 loads
    float4 pf[16];
#pragma unroll
    for (int kk = 0; kk < 8; ++kk) {
        pf[2 * kk]     = *reinterpret_cast<const float4*>(arow + kk * 32);
        pf[2 * kk + 1] = *reinterpret_cast<const float4*>(arow + kk * 32 + 4);
    }
    // pin all prefetched values live so the compiler can't re-sink the loads
#pragma unroll
    for (int i = 0; i < 16; ++i)
        asm volatile("" : "+v"(pf[i].x), "+v"(pf[i].y), "+v"(pf[i].z), "+v"(pf[i].w));

    f32x4 acc[16];
#pragma unroll
    for (int nt = 0; nt < 16; ++nt) acc[nt] = (f32x4){0.f, 0.f, 0.f, 0.f};

    const unsigned short* wb = Wt + (size_t)r16 * CH + q * 8;

#pragma unroll
    for (int kk = 0; kk < 8; ++kk) {
        bf16x8 af;
        af[0] = (short)f2bf(pf[2 * kk].x);     af[1] = (short)f2bf(pf[2 * kk].y);
        af[2] = (short)f2bf(pf[2 * kk].z);     af[3] = (short)f2bf(pf[2 * kk].w);
        af[4] = (short)f2bf(pf[2 * kk + 1].x); af[5] = (short)f2bf(pf[2 * kk + 1].y);
        af[6] = (short)f2bf(pf[2 * kk + 1].z); af[7] = (short)f2bf(pf[2 * kk + 1].w);
#pragma unroll
        for (int nt = 0; nt < 16; ++nt) {
            bf16x8 b = *reinterpret_cast<const bf16x8*>(wb + (size_t)nt * 16 * CH + kk * 32);
            acc[nt] = __builtin_amdgcn_mfma_f32_16x16x32_bf16(af, b, acc[nt], 0, 0, 0);
        }
    }

    // epilogue: Z bf16
    const int crow = rb + q * 4;
#pragma unroll
    for (int nt = 0; nt < 16; ++nt) {
        unsigned short* po = zbf + (size_t)crow * CH + nt * 16 + r16;
#pragma unroll
        for (int r = 0; r < 4; ++r) po[(size_t)r * CH] = f2bf(acc[nt][r]);
    }
}

// K2: out[row] = norm[row] * (Z[row] + sum_e Z[elist[e]]), f32 out.
__global__ __launch_bounds__(256) void k_gout(const unsigned short* __restrict__ zbf,
                                              const int* __restrict__ off,
                                              const int* __restrict__ deg,
                                              const int* __restrict__ elist,
                                              const float* __restrict__ norm,
                                              float* __restrict__ out) {
    int wid = threadIdx.x >> 6;
    int lane = threadIdx.x & 63;
    int row = blockIdx.x * 4 + wid;
    if (row >= NN) return;
    int start = off[row];
    int d = deg[row];
    const int uo = lane * 4;
    ushort4 bv = *reinterpret_cast<const ushort4*>(zbf + (size_t)row * CH + uo);
    float ax = bf2f(bv.x), ay = bf2f(bv.y), az = bf2f(bv.z), aw = bf2f(bv.w);
    int e = 0;
    while (e < d) {
        int i0 = (e + 0 < d) ? elist[start + e + 0] : -1;
        int i1 = (e + 1 < d) ? elist[start + e + 1] : -1;
        int i2 = (e + 2 < d) ? elist[start + e + 2] : -1;
        int i3 = (e + 3 < d) ? elist[start + e + 3] : -1;
        int i4 = (e + 4 < d) ? elist[start + e + 4] : -1;
        int i5 = (e + 5 < d) ? elist[start + e + 5] : -1;
        int i6 = (e + 6 < d) ? elist[start + e + 6] : -1;
        int i7 = (e + 7 < d) ? elist[start + e + 7] : -1;
#define GACC(ii) if (ii >= 0) { \
            ushort4 v = *reinterpret_cast<const ushort4*>(zbf + (size_t)ii * CH + uo); \
            ax += bf2f(v.x); ay += bf2f(v.y); az += bf2f(v.z); aw += bf2f(v.w); }
        GACC(i0) GACC(i1) GACC(i2) GACC(i3) GACC(i4) GACC(i5) GACC(i6) GACC(i7)
#undef GACC
        e += 8;
    }
    const float nv = norm[row];
    float4 o;
    o.x = ax * nv; o.y = ay * nv; o.z = az * nv; o.w = aw * nv;
    *reinterpret_cast<float4*>(out + (size_t)row * CH + uo) = o;
}

// ---------------- Path B (fallback: fused f32 kernel) ----------------
__global__ __launch_bounds__(256, 4) void k_fgg(const float* __restrict__ x,
                                                const int* __restrict__ off,
                                                const int* __restrict__ deg,
                                                const int* __restrict__ elist,
                                                const float* __restrict__ norm,
                                                const unsigned short* __restrict__ Wt,
                                                float* __restrict__ out) {
    __shared__ unsigned short lds_a[64 * CH];
    const int tid = threadIdx.x;
    const int wid = tid >> 6;
    const int lane = tid & 63;
    const int rb = blockIdx.x * 64;
    const int rowbase = rb + wid * 16;
    const int r16 = lane & 15;
    const int q = lane >> 4;
    const int fo4 = lane * 4;

    const int offv = off[rowbase + r16];
    const int degv = deg[rowbase + r16];
    const float nv = norm[rb + lane];

    float4 acc[16];
#pragma unroll
    for (int r = 0; r < 16; ++r)
        acc[r] = *reinterpret_cast<const float4*>(x + (size_t)(rowbase + r) * CH + fo4);

#pragma unroll
    for (int r = 0; r < 16; ++r) {
        const int start = __shfl(offv, r);
        const int d = __shfl(degv, r);
        int e = 0;
        while (e < d) {
            int i0 = (e + 0 < d) ? elist[start + e + 0] : -1;
            int i1 = (e + 1 < d) ? elist[start + e + 1] : -1;
            int i2 = (e + 2 < d) ? elist[start + e + 2] : -1;
            int i3 = (e + 3 < d) ? elist[start + e + 3] : -1;
#define GACC(ii) if (ii >= 0) { \
            float4 v = *reinterpret_cast<const float4*>(x + (size_t)ii * CH + fo4); \
            acc[r].x += v.x; acc[r].y += v.y; acc[r].z += v.z; acc[r].w += v.w; }
            GACC(i0) GACC(i1) GACC(i2) GACC(i3)
#undef GACC
            e += 4;
        }
    }

    unsigned short* lb = lds_a + wid * 16 * CH;
#pragma unroll
    for (int r = 0; r < 16; ++r) {
        ushort4 w;
        w.x = f2bf(acc[r].x); w.y = f2bf(acc[r].y);
        w.z = f2bf(acc[r].z); w.w = f2bf(acc[r].w);
        const int gs = (lane >> 1) ^ (r & 7);
        *reinterpret_cast<ushort4*>(lb + r * CH + gs * 8 + (lane & 1) * 4) = w;
    }
    __syncthreads();

    f32x4 facc[4][4];
#pragma unroll
    for (int m = 0; m < 4; ++m)
#pragma unroll
        for (int nt = 0; nt < 4; ++nt) facc[m][nt] = (f32x4){0.f, 0.f, 0.f, 0.f};

    const unsigned short* wb = Wt + (size_t)(wid * 64 + r16) * CH + q * 8;

#pragma unroll
    for (int kk = 0; kk < 8; ++kk) {
        bf16x8 b[4];
#pragma unroll
        for (int nt = 0; nt < 4; ++nt)
            b[nt] = *reinterpret_cast<const bf16x8*>(wb + (size_t)nt * 16 * CH + kk * 32);
        bf16x8 a[4];
#pragma unroll
        for (int m = 0; m < 4; ++m) {
            const int lr = m * 16 + r16;
            const int idx = lr * CH + ((((kk * 4) + q) ^ (lr & 7)) << 3);
            a[m] = *reinterpret_cast<const bf16x8*>(&lds_a[idx]);
        }
#pragma unroll
        for (int m = 0; m < 4; ++m)
#pragma unroll
            for (int nt = 0; nt < 4; ++nt)
                facc[m][nt] = __builtin_amdgcn_mfma_f32_16x16x32_bf16(a[m], b[nt], facc[m][nt], 0, 0, 0);
    }

#pragma unroll
    for (int m = 0; m < 4; ++m) {
        const int crow = rb + m * 16 + q * 4;
#pragma unroll
        for (int nt = 0; nt < 4; ++nt) {
            float* po = out + (size_t)crow * CH + wid * 64 + nt * 16 + r16;
#pragma unroll
            for (int r = 0; r < 4; ++r) {
                const float nj = __shfl(nv, m * 16 + q * 4 + r);
                po[(size_t)r * CH] = facc[m][nt][r] * nj;
            }
        }
    }
}

extern "C" void kernel_launch(void* const* d_in, const int* in_sizes, int n_in,
                              void* d_out, int out_size, void* d_ws, size_t ws_size,
                              hipStream_t stream) {
    const float* x = (const float*)d_in[0];
    const int* se = (const int*)d_in[1];
    const int* te = (const int*)d_in[2];
    const float* norm = (const float*)d_in[3];
    const float* W = (const float*)d_in[4];
    float* out = (float*)d_out;

    char* ws = (char*)d_ws;
    unsigned short* Wt = (unsigned short*)ws;             // 128 KB
    int* deg   = (int*)(ws + 131072);                     // 800 KB
    int* off   = (int*)(ws + 931072);                     // 800 KB
    int* cur   = (int*)(ws + 1731072);                    // 800 KB
    int* elist = (int*)(ws + 2531072);                    // 2.4 MB
    int* bsum  = (int*)(ws + 4931072);                    // 1 KB
    const size_t ZBF_OFF = 4932096;
    const size_t NEED = ZBF_OFF + (size_t)NN * CH * 2;    // ~107.3 MB
    const bool big = (ws_size >= NEED);
    unsigned short* zbf = (unsigned short*)(ws + ZBF_OFF);

    hipMemsetAsync(deg, 0, NN * sizeof(int), stream);
    if (big) {
        k_wt<<<CH, CH, 0, stream>>>(W, Wt);
        k_zw<<<NN / 64, 256, 0, stream>>>(x, Wt, zbf, te, deg);
        k_scanA<<<NBLK_SCAN, 256, 0, stream>>>(deg, off, bsum);
        k_scanC<<<NBLK_SCAN, 256, 0, stream>>>(off, bsum, cur);
        k_fill<<<(NE + 255) / 256, 256, 0, stream>>>(se, te, cur, elist);
        k_gout<<<NN / 4, 256, 0, stream>>>(zbf, off, deg, elist, norm, out);
    } else {
        k_prep<<<512, 256, 0, stream>>>(W, Wt, te, deg);
        k_scanA<<<NBLK_SCAN, 256, 0, stream>>>(deg, off, bsum);
        k_scanC<<<NBLK_SCAN, 256, 0, stream>>>(off, bsum, cur);
        k_fill<<<(NE + 255) / 256, 256, 0, stream>>>(se, te, cur, elist);
        k_fgg<<<NN / 64, 256, 0, stream>>>(x, off, deg, elist, norm, Wt, out);
    }
}

// Round 17
// 239.391 us; speedup vs baseline: 1.7331x; 1.7331x over previous
//
#include <hip/hip_runtime.h>
#include <hip/hip_bf16.h>

#define NN 200000
#define NE 600000
#define CH 256
#define NBLK_SCAN 196   // ceil(200000/1024)
#define ZW_GRID 512
#define ZW_TILES 6250   // NN / 32 exactly

typedef short bf16x8 __attribute__((ext_vector_type(8)));
typedef float f32x4 __attribute__((ext_vector_type(4)));
typedef unsigned short ushort8v __attribute__((ext_vector_type(8)));

__device__ __forceinline__ unsigned short f2bf(float f) {
    unsigned int u = __builtin_bit_cast(unsigned int, f);
    u = (u + 0x7FFFu + ((u >> 16) & 1u)) >> 16;
    return (unsigned short)u;
}
__device__ __forceinline__ float bf2f(unsigned short u) {
    unsigned int v = ((unsigned int)u) << 16;
    return __builtin_bit_cast(float, v);
}

// Wt[j][k] = bf16(W[k][j])
__global__ void k_wt(const float* __restrict__ W, unsigned short* __restrict__ Wt) {
    int j = blockIdx.x, k = threadIdx.x;
    Wt[j * CH + k] = f2bf(W[k * CH + j]);
}

// prep for fallback path: Wt + degree count
__global__ __launch_bounds__(256) void k_prep(const float* __restrict__ W,
                                              unsigned short* __restrict__ Wt,
                                              const int* __restrict__ te,
                                              int* __restrict__ deg) {
    const int t = blockIdx.x * 256 + threadIdx.x;
    const int S = gridDim.x * 256;
    for (int e = t; e < NE; e += S) atomicAdd(&deg[te[e]], 1);
    for (int i = t; i < CH * CH; i += S) {
        int j = i >> 8, k = i & 255;
        Wt[j * CH + k] = f2bf(W[k * CH + j]);
    }
}

__global__ __launch_bounds__(256) void k_scanA(const int* __restrict__ deg,
                                               int* __restrict__ off,
                                               int* __restrict__ bsum) {
    __shared__ int ts[256];
    int tid = threadIdx.x;
    int base = blockIdx.x * 1024 + tid * 4;
    int v[4];
#pragma unroll
    for (int j = 0; j < 4; ++j) {
        int idx = base + j;
        v[j] = (idx < NN) ? deg[idx] : 0;
    }
    int tsum = v[0] + v[1] + v[2] + v[3];
    ts[tid] = tsum;
    __syncthreads();
    int x = tsum;
    for (int ofs = 1; ofs < 256; ofs <<= 1) {
        int y = (tid >= ofs) ? ts[tid - ofs] : 0;
        __syncthreads();
        x += y;
        ts[tid] = x;
        __syncthreads();
    }
    int run = x - tsum;
#pragma unroll
    for (int j = 0; j < 4; ++j) {
        int idx = base + j;
        if (idx < NN) off[idx] = run;
        run += v[j];
    }
    if (tid == 255) bsum[blockIdx.x] = x;
}

// scanC: every block locally scans the 196 block sums, applies its prefix
__global__ __launch_bounds__(256) void k_scanC(int* __restrict__ off,
                                               const int* __restrict__ bsum,
                                               int* __restrict__ cur) {
    __shared__ int ts[256];
    int tid = threadIdx.x;
    int v = (tid < NBLK_SCAN) ? bsum[tid] : 0;
    ts[tid] = v;
    __syncthreads();
    int x = v;
    for (int ofs = 1; ofs < 256; ofs <<= 1) {
        int y = (tid >= ofs) ? ts[tid - ofs] : 0;
        __syncthreads();
        x += y;
        ts[tid] = x;
        __syncthreads();
    }
    const int bo = (blockIdx.x == 0) ? 0 : ts[blockIdx.x - 1];
    int base = blockIdx.x * 1024 + tid * 4;
#pragma unroll
    for (int j = 0; j < 4; ++j) {
        int idx = base + j;
        if (idx < NN) {
            int o = off[idx] + bo;
            off[idx] = o;
            cur[idx] = o;
        }
    }
}

__global__ void k_fill(const int* __restrict__ se, const int* __restrict__ te,
                       int* __restrict__ cur, int* __restrict__ elist) {
    int e = blockIdx.x * 256 + threadIdx.x;
    if (e < NE) {
        int t = te[e];
        int pos = atomicAdd(&cur[t], 1);
        elist[pos] = se[e];
    }
}

// ---------------- Path A ----------------
// K1: Z = x @ W (bf16 out). Persistent blocks, 32-row tiles, LDS double-buffer,
// B (wave's 64-col Wt slice) held in registers for the whole kernel.
// CORRECTED 2-phase pipeline (guide T3 minimal recipe): STAGE(next) issued
// BEFORE compute, single __syncthreads() (vmcnt(0)+barrier) AFTER compute —
// next-tile global_load_lds stay in flight across the MFMA phase.
__global__ __launch_bounds__(256, 2) void k_zw(const float* __restrict__ x,
                                               const unsigned short* __restrict__ Wt,
                                               unsigned short* __restrict__ zbf,
                                               const int* __restrict__ te,
                                               int* __restrict__ deg) {
    __shared__ float lds[2][32 * CH];   // 2 x 32 KB
    const int tid = threadIdx.x;
    const int wid = tid >> 6;
    const int lane = tid & 63;
    const int r16 = lane & 15;
    const int q = lane >> 4;

#define STAGE(buf, tile)                                                                  \
    {                                                                                     \
        const float* src = x + (size_t)(tile) * 32 * CH;                                  \
        _Pragma("unroll")                                                                 \
        for (int i = 0; i < 8; ++i) {                                                     \
            const int fi = i * 1024 + tid * 4;                                            \
            const int row = fi >> 8;                                                      \
            const int g = (fi & 255) >> 2;                                                \
            const int sg = g ^ (row & 7);                                                 \
            __builtin_amdgcn_global_load_lds(                                             \
                (const __attribute__((address_space(1))) void*)(src + row * CH + sg * 4), \
                (__attribute__((address_space(3))) void*)(&lds[buf][fi]), 16, 0, 0);      \
        }                                                                                 \
    }

    int t = blockIdx.x;
    STAGE(0, t)

    // B slice -> registers (loaded once; L2-broadcast across blocks)
    bf16x8 breg[8][4];
    {
        const unsigned short* wb = Wt + (size_t)(wid * 64 + r16) * CH + q * 8;
#pragma unroll
        for (int kk = 0; kk < 8; ++kk)
#pragma unroll
            for (int nt = 0; nt < 4; ++nt)
                breg[kk][nt] = *reinterpret_cast<const bf16x8*>(wb + (size_t)nt * 16 * CH + kk * 32);
    }

    // fused degree count (overlaps stage + B-load latency)
    for (int e = blockIdx.x * 256 + tid; e < NE; e += ZW_GRID * 256)
        atomicAdd(&deg[te[e]], 1);

    __syncthreads();   // prologue: first tile resident

    int cur = 0;
    for (; t < ZW_TILES; t += ZW_GRID) {
        const int tn = t + ZW_GRID;
        if (tn < ZW_TILES) STAGE(cur ^ 1, tn)   // in flight during compute below

        f32x4 acc[2][4];
#pragma unroll
        for (int m = 0; m < 2; ++m)
#pragma unroll
            for (int nt = 0; nt < 4; ++nt) acc[m][nt] = (f32x4){0.f, 0.f, 0.f, 0.f};

#pragma unroll
        for (int kk = 0; kk < 8; ++kk) {
            bf16x8 a[2];
#pragma unroll
            for (int m = 0; m < 2; ++m) {
                const int lr = m * 16 + r16;
                const int sw = lr & 7;
                const float* lp = &lds[cur][lr * CH];
                const int g0 = kk * 8 + q * 2;
                f32x4 lo = *reinterpret_cast<const f32x4*>(lp + ((g0 ^ sw) << 2));
                f32x4 hi = *reinterpret_cast<const f32x4*>(lp + (((g0 + 1) ^ sw) << 2));
                a[m][0] = (short)f2bf(lo[0]); a[m][1] = (short)f2bf(lo[1]);
                a[m][2] = (short)f2bf(lo[2]); a[m][3] = (short)f2bf(lo[3]);
                a[m][4] = (short)f2bf(hi[0]); a[m][5] = (short)f2bf(hi[1]);
                a[m][6] = (short)f2bf(hi[2]); a[m][7] = (short)f2bf(hi[3]);
            }
#pragma unroll
            for (int m = 0; m < 2; ++m)
#pragma unroll
                for (int nt = 0; nt < 4; ++nt)
                    acc[m][nt] = __builtin_amdgcn_mfma_f32_16x16x32_bf16(a[m], breg[kk][nt], acc[m][nt], 0, 0, 0);
        }

        // store Z tile (bf16)
        const int rb = t * 32;
#pragma unroll
        for (int m = 0; m < 2; ++m) {
#pragma unroll
            for (int nt = 0; nt < 4; ++nt) {
                unsigned short* po = zbf + (size_t)(rb + m * 16 + q * 4) * CH
                                   + wid * 64 + nt * 16 + r16;
#pragma unroll
                for (int r = 0; r < 4; ++r) po[(size_t)r * CH] = f2bf(acc[m][nt][r]);
            }
        }

        __syncthreads();   // single per-tile barrier: drains next-tile stage
                           // AFTER compute + guards buffer reuse
        cur ^= 1;
    }
#undef STAGE
}

// K2: out[row] = norm[row] * (Z[row] + sum_e Z[elist[e]]), f32 out.
__global__ __launch_bounds__(256) void k_gout(const unsigned short* __restrict__ zbf,
                                              const int* __restrict__ off,
                                              const int* __restrict__ deg,
                                              const int* __restrict__ elist,
                                              const float* __restrict__ norm,
                                              float* __restrict__ out) {
    int wid = threadIdx.x >> 6;
    int lane = threadIdx.x & 63;
    int row = blockIdx.x * 4 + wid;
    if (row >= NN) return;
    int start = off[row];
    int d = deg[row];
    const int uo = lane * 4;
    ushort4 bv = *reinterpret_cast<const ushort4*>(zbf + (size_t)row * CH + uo);
    float ax = bf2f(bv.x), ay = bf2f(bv.y), az = bf2f(bv.z), aw = bf2f(bv.w);
    int e = 0;
    while (e < d) {
        int i0 = (e + 0 < d) ? elist[start + e + 0] : -1;
        int i1 = (e + 1 < d) ? elist[start + e + 1] : -1;
        int i2 = (e + 2 < d) ? elist[start + e + 2] : -1;
        int i3 = (e + 3 < d) ? elist[start + e + 3] : -1;
        int i4 = (e + 4 < d) ? elist[start + e + 4] : -1;
        int i5 = (e + 5 < d) ? elist[start + e + 5] : -1;
        int i6 = (e + 6 < d) ? elist[start + e + 6] : -1;
        int i7 = (e + 7 < d) ? elist[start + e + 7] : -1;
#define GACC(ii) if (ii >= 0) { \
            ushort4 v = *reinterpret_cast<const ushort4*>(zbf + (size_t)ii * CH + uo); \
            ax += bf2f(v.x); ay += bf2f(v.y); az += bf2f(v.z); aw += bf2f(v.w); }
        GACC(i0) GACC(i1) GACC(i2) GACC(i3) GACC(i4) GACC(i5) GACC(i6) GACC(i7)
#undef GACC
        e += 8;
    }
    const float nv = norm[row];
    float4 o;
    o.x = ax * nv; o.y = ay * nv; o.z = az * nv; o.w = aw * nv;
    *reinterpret_cast<float4*>(out + (size_t)row * CH + uo) = o;
}

// ---------------- Path B (fallback: fused f32 kernel) ----------------
__global__ __launch_bounds__(256, 4) void k_fgg(const float* __restrict__ x,
                                                const int* __restrict__ off,
                                                const int* __restrict__ deg,
                                                const int* __restrict__ elist,
                                                const float* __restrict__ norm,
                                                const unsigned short* __restrict__ Wt,
                                                float* __restrict__ out) {
    __shared__ unsigned short lds_a[64 * CH];
    const int tid = threadIdx.x;
    const int wid = tid >> 6;
    const int lane = tid & 63;
    const int rb = blockIdx.x * 64;
    const int rowbase = rb + wid * 16;
    const int r16 = lane & 15;
    const int q = lane >> 4;
    const int fo4 = lane * 4;

    const int offv = off[rowbase + r16];
    const int degv = deg[rowbase + r16];
    const float nv = norm[rb + lane];

    float4 acc[16];
#pragma unroll
    for (int r = 0; r < 16; ++r)
        acc[r] = *reinterpret_cast<const float4*>(x + (size_t)(rowbase + r) * CH + fo4);

#pragma unroll
    for (int r = 0; r < 16; ++r) {
        const int start = __shfl(offv, r);
        const int d = __shfl(degv, r);
        int e = 0;
        while (e < d) {
            int i0 = (e + 0 < d) ? elist[start + e + 0] : -1;
            int i1 = (e + 1 < d) ? elist[start + e + 1] : -1;
            int i2 = (e + 2 < d) ? elist[start + e + 2] : -1;
            int i3 = (e + 3 < d) ? elist[start + e + 3] : -1;
#define GACC(ii) if (ii >= 0) { \
            float4 v = *reinterpret_cast<const float4*>(x + (size_t)ii * CH + fo4); \
            acc[r].x += v.x; acc[r].y += v.y; acc[r].z += v.z; acc[r].w += v.w; }
            GACC(i0) GACC(i1) GACC(i2) GACC(i3)
#undef GACC
            e += 4;
        }
    }

    unsigned short* lb = lds_a + wid * 16 * CH;
#pragma unroll
    for (int r = 0; r < 16; ++r) {
        ushort4 w;
        w.x = f2bf(acc[r].x); w.y = f2bf(acc[r].y);
        w.z = f2bf(acc[r].z); w.w = f2bf(acc[r].w);
        const int gs = (lane >> 1) ^ (r & 7);
        *reinterpret_cast<ushort4*>(lb + r * CH + gs * 8 + (lane & 1) * 4) = w;
    }
    __syncthreads();

    f32x4 facc[4][4];
#pragma unroll
    for (int m = 0; m < 4; ++m)
#pragma unroll
        for (int nt = 0; nt < 4; ++nt) facc[m][nt] = (f32x4){0.f, 0.f, 0.f, 0.f};

    const unsigned short* wb = Wt + (size_t)(wid * 64 + r16) * CH + q * 8;

#pragma unroll
    for (int kk = 0; kk < 8; ++kk) {
        bf16x8 b[4];
#pragma unroll
        for (int nt = 0; nt < 4; ++nt)
            b[nt] = *reinterpret_cast<const bf16x8*>(wb + (size_t)nt * 16 * CH + kk * 32);
        bf16x8 a[4];
#pragma unroll
        for (int m = 0; m < 4; ++m) {
            const int lr = m * 16 + r16;
            const int idx = lr * CH + ((((kk * 4) + q) ^ (lr & 7)) << 3);
            a[m] = *reinterpret_cast<const bf16x8*>(&lds_a[idx]);
        }
#pragma unroll
        for (int m = 0; m < 4; ++m)
#pragma unroll
            for (int nt = 0; nt < 4; ++nt)
                facc[m][nt] = __builtin_amdgcn_mfma_f32_16x16x32_bf16(a[m], b[nt], facc[m][nt], 0, 0, 0);
    }

#pragma unroll
    for (int m = 0; m < 4; ++m) {
        const int crow = rb + m * 16 + q * 4;
#pragma unroll
        for (int nt = 0; nt < 4; ++nt) {
            float* po = out + (size_t)crow * CH + wid * 64 + nt * 16 + r16;
#pragma unroll
            for (int r = 0; r < 4; ++r) {
                const float nj = __shfl(nv, m * 16 + q * 4 + r);
                po[(size_t)r * CH] = facc[m][nt][r] * nj;
            }
        }
    }
}

extern "C" void kernel_launch(void* const* d_in, const int* in_sizes, int n_in,
                              void* d_out, int out_size, void* d_ws, size_t ws_size,
                              hipStream_t stream) {
    const float* x = (const float*)d_in[0];
    const int* se = (const int*)d_in[1];
    const int* te = (const int*)d_in[2];
    const float* norm = (const float*)d_in[3];
    const float* W = (const float*)d_in[4];
    float* out = (float*)d_out;

    char* ws = (char*)d_ws;
    unsigned short* Wt = (unsigned short*)ws;             // 128 KB
    int* deg   = (int*)(ws + 131072);                     // 800 KB
    int* off   = (int*)(ws + 931072);                     // 800 KB
    int* cur   = (int*)(ws + 1731072);                    // 800 KB
    int* elist = (int*)(ws + 2531072);                    // 2.4 MB
    int* bsum  = (int*)(ws + 4931072);                    // 1 KB
    const size_t ZBF_OFF = 4932096;
    const size_t NEED = ZBF_OFF + (size_t)NN * CH * 2;    // ~107.3 MB
    const bool big = (ws_size >= NEED);
    unsigned short* zbf = (unsigned short*)(ws + ZBF_OFF);

    hipMemsetAsync(deg, 0, NN * sizeof(int), stream);
    if (big) {
        k_wt<<<CH, CH, 0, stream>>>(W, Wt);
        k_zw<<<ZW_GRID, 256, 0, stream>>>(x, Wt, zbf, te, deg);
        k_scanA<<<NBLK_SCAN, 256, 0, stream>>>(deg, off, bsum);
        k_scanC<<<NBLK_SCAN, 256, 0, stream>>>(off, bsum, cur);
        k_fill<<<(NE + 255) / 256, 256, 0, stream>>>(se, te, cur, elist);
        k_gout<<<NN / 4, 256, 0, stream>>>(zbf, off, deg, elist, norm, out);
    } else {
        k_prep<<<512, 256, 0, stream>>>(W, Wt, te, deg);
        k_scanA<<<NBLK_SCAN, 256, 0, stream>>>(deg, off, bsum);
        k_scanC<<<NBLK_SCAN, 256, 0, stream>>>(off, bsum, cur);
        k_fill<<<(NE + 255) / 256, 256, 0, stream>>>(se, te, cur, elist);
        k_fgg<<<NN / 64, 256, 0, stream>>>(x, off, deg, elist, norm, Wt, out);
    }
}

// Round 18
// 238.167 us; speedup vs baseline: 1.7420x; 1.0051x over previous
//
#include <hip/hip_runtime.h>
#include <hip/hip_bf16.h>

#define NN 200000
#define NE 600000
#define CH 256
#define NBLK_SCAN 196   // ceil(200000/1024)
#define ZW_GRID 512
#define ZW_TILES 6250   // NN / 32 exactly

typedef short bf16x8 __attribute__((ext_vector_type(8)));
typedef float f32x4 __attribute__((ext_vector_type(4)));
typedef unsigned short ushort8v __attribute__((ext_vector_type(8)));

__device__ __forceinline__ unsigned short f2bf(float f) {
    unsigned int u = __builtin_bit_cast(unsigned int, f);
    u = (u + 0x7FFFu + ((u >> 16) & 1u)) >> 16;
    return (unsigned short)u;
}
__device__ __forceinline__ float bf2f(unsigned short u) {
    unsigned int v = ((unsigned int)u) << 16;
    return __builtin_bit_cast(float, v);
}

// Wt[j][k] = bf16(W[k][j])
__global__ void k_wt(const float* __restrict__ W, unsigned short* __restrict__ Wt) {
    int j = blockIdx.x, k = threadIdx.x;
    Wt[j * CH + k] = f2bf(W[k * CH + j]);
}

// prep for fallback path: Wt + degree count
__global__ __launch_bounds__(256) void k_prep(const float* __restrict__ W,
                                              unsigned short* __restrict__ Wt,
                                              const int* __restrict__ te,
                                              int* __restrict__ deg) {
    const int t = blockIdx.x * 256 + threadIdx.x;
    const int S = gridDim.x * 256;
    for (int e = t; e < NE; e += S) atomicAdd(&deg[te[e]], 1);
    for (int i = t; i < CH * CH; i += S) {
        int j = i >> 8, k = i & 255;
        Wt[j * CH + k] = f2bf(W[k * CH + j]);
    }
}

__global__ __launch_bounds__(256) void k_scanA(const int* __restrict__ deg,
                                               int* __restrict__ off,
                                               int* __restrict__ bsum) {
    __shared__ int ts[256];
    int tid = threadIdx.x;
    int base = blockIdx.x * 1024 + tid * 4;
    int v[4];
#pragma unroll
    for (int j = 0; j < 4; ++j) {
        int idx = base + j;
        v[j] = (idx < NN) ? deg[idx] : 0;
    }
    int tsum = v[0] + v[1] + v[2] + v[3];
    ts[tid] = tsum;
    __syncthreads();
    int x = tsum;
    for (int ofs = 1; ofs < 256; ofs <<= 1) {
        int y = (tid >= ofs) ? ts[tid - ofs] : 0;
        __syncthreads();
        x += y;
        ts[tid] = x;
        __syncthreads();
    }
    int run = x - tsum;
#pragma unroll
    for (int j = 0; j < 4; ++j) {
        int idx = base + j;
        if (idx < NN) off[idx] = run;
        run += v[j];
    }
    if (tid == 255) bsum[blockIdx.x] = x;
}

// scanC: every block locally scans the 196 block sums, applies its prefix
__global__ __launch_bounds__(256) void k_scanC(int* __restrict__ off,
                                               const int* __restrict__ bsum,
                                               int* __restrict__ cur) {
    __shared__ int ts[256];
    int tid = threadIdx.x;
    int v = (tid < NBLK_SCAN) ? bsum[tid] : 0;
    ts[tid] = v;
    __syncthreads();
    int x = v;
    for (int ofs = 1; ofs < 256; ofs <<= 1) {
        int y = (tid >= ofs) ? ts[tid - ofs] : 0;
        __syncthreads();
        x += y;
        ts[tid] = x;
        __syncthreads();
    }
    const int bo = (blockIdx.x == 0) ? 0 : ts[blockIdx.x - 1];
    int base = blockIdx.x * 1024 + tid * 4;
#pragma unroll
    for (int j = 0; j < 4; ++j) {
        int idx = base + j;
        if (idx < NN) {
            int o = off[idx] + bo;
            off[idx] = o;
            cur[idx] = o;
        }
    }
}

__global__ void k_fill(const int* __restrict__ se, const int* __restrict__ te,
                       int* __restrict__ cur, int* __restrict__ elist) {
    int e = blockIdx.x * 256 + threadIdx.x;
    if (e < NE) {
        int t = te[e];
        int pos = atomicAdd(&cur[t], 1);
        elist[pos] = se[e];
    }
}

// ---------------- Path A ----------------
// K1: Z = x @ W (bf16 out). R12 structure + T4 counted-vmcnt pipeline:
// raw s_barrier (no vmcnt drain) + explicit s_waitcnt vmcnt(40) before the
// ds_reads. Per-wave issue order per tile: loads_t(8), stores_{t-1}(32),
// loads_{t+1}(8) => vmcnt(40) completes exactly tile t's stage while leaving
// stores + next-tile loads in flight across the compute phase.
__global__ __launch_bounds__(256, 2) void k_zw(const float* __restrict__ x,
                                               const unsigned short* __restrict__ Wt,
                                               unsigned short* __restrict__ zbf,
                                               const int* __restrict__ te,
                                               int* __restrict__ deg) {
    __shared__ float lds[2][32 * CH];   // 2 x 32 KB
    const int tid = threadIdx.x;
    const int wid = tid >> 6;
    const int lane = tid & 63;
    const int r16 = lane & 15;
    const int q = lane >> 4;

#define STAGE(buf, tile)                                                                  \
    {                                                                                     \
        const float* src = x + (size_t)(tile) * 32 * CH;                                  \
        _Pragma("unroll")                                                                 \
        for (int i = 0; i < 8; ++i) {                                                     \
            const int fi = i * 1024 + tid * 4;                                            \
            const int row = fi >> 8;                                                      \
            const int g = (fi & 255) >> 2;                                                \
            const int sg = g ^ (row & 7);                                                 \
            __builtin_amdgcn_global_load_lds(                                             \
                (const __attribute__((address_space(1))) void*)(src + row * CH + sg * 4), \
                (__attribute__((address_space(3))) void*)(&lds[buf][fi]), 16, 0, 0);      \
        }                                                                                 \
    }

    int t = blockIdx.x;

    // prologue: first stage + B regs + deg count, then full drain ONCE so the
    // steady-state vmcnt arithmetic starts from zero outstanding.
    STAGE(0, t)

    bf16x8 breg[8][4];
    {
        const unsigned short* wb = Wt + (size_t)(wid * 64 + r16) * CH + q * 8;
#pragma unroll
        for (int kk = 0; kk < 8; ++kk)
#pragma unroll
            for (int nt = 0; nt < 4; ++nt)
                breg[kk][nt] = *reinterpret_cast<const bf16x8*>(wb + (size_t)nt * 16 * CH + kk * 32);
    }
    for (int e = blockIdx.x * 256 + tid; e < NE; e += ZW_GRID * 256)
        atomicAdd(&deg[te[e]], 1);

    asm volatile("s_waitcnt vmcnt(0)" ::: "memory");
    __builtin_amdgcn_s_barrier();

    int cur = 0;
    for (; t < ZW_TILES; t += ZW_GRID) {
        const int tn = t + ZW_GRID;
        if (tn < ZW_TILES) {
            STAGE(cur ^ 1, tn)   // stays in flight through compute below
            // outstanding <= stores_prev(32) + loads_next(8) + loads_cur(8)=48;
            // oldest 8 = this tile's stage -> done after vmcnt(40)
            asm volatile("s_waitcnt vmcnt(40)" ::: "memory");
        } else {
            // no next stage: outstanding <= stores_prev(32) + loads_cur(8)=40
            asm volatile("s_waitcnt vmcnt(32)" ::: "memory");
        }

        f32x4 acc[2][4];
#pragma unroll
        for (int m = 0; m < 2; ++m)
#pragma unroll
            for (int nt = 0; nt < 4; ++nt) acc[m][nt] = (f32x4){0.f, 0.f, 0.f, 0.f};

#pragma unroll
        for (int kk = 0; kk < 8; ++kk) {
            bf16x8 a[2];
#pragma unroll
            for (int m = 0; m < 2; ++m) {
                const int lr = m * 16 + r16;
                const int sw = lr & 7;
                const float* lp = &lds[cur][lr * CH];
                const int g0 = kk * 8 + q * 2;
                f32x4 lo = *reinterpret_cast<const f32x4*>(lp + ((g0 ^ sw) << 2));
                f32x4 hi = *reinterpret_cast<const f32x4*>(lp + (((g0 + 1) ^ sw) << 2));
                a[m][0] = (short)f2bf(lo[0]); a[m][1] = (short)f2bf(lo[1]);
                a[m][2] = (short)f2bf(lo[2]); a[m][3] = (short)f2bf(lo[3]);
                a[m][4] = (short)f2bf(hi[0]); a[m][5] = (short)f2bf(hi[1]);
                a[m][6] = (short)f2bf(hi[2]); a[m][7] = (short)f2bf(hi[3]);
            }
#pragma unroll
            for (int m = 0; m < 2; ++m)
#pragma unroll
                for (int nt = 0; nt < 4; ++nt)
                    acc[m][nt] = __builtin_amdgcn_mfma_f32_16x16x32_bf16(a[m], breg[kk][nt], acc[m][nt], 0, 0, 0);
        }

        // store Z tile (bf16): 32 store instrs/wave, left in flight (counted above)
        const int rb = t * 32;
#pragma unroll
        for (int m = 0; m < 2; ++m) {
#pragma unroll
            for (int nt = 0; nt < 4; ++nt) {
                unsigned short* po = zbf + (size_t)(rb + m * 16 + q * 4) * CH
                                   + wid * 64 + nt * 16 + r16;
#pragma unroll
                for (int r = 0; r < 4; ++r) po[(size_t)r * CH] = f2bf(acc[m][nt][r]);
            }
        }

        // raw barrier: buffer-reuse safety (each wave's ds_reads were consumed
        // by its MFMAs before reaching here); NO vmcnt drain.
        __builtin_amdgcn_s_barrier();
        cur ^= 1;
    }
#undef STAGE
}

// K2: out[row] = norm[row] * (Z[row] + sum_e Z[elist[e]]), f32 out.
__global__ __launch_bounds__(256) void k_gout(const unsigned short* __restrict__ zbf,
                                              const int* __restrict__ off,
                                              const int* __restrict__ deg,
                                              const int* __restrict__ elist,
                                              const float* __restrict__ norm,
                                              float* __restrict__ out) {
    int wid = threadIdx.x >> 6;
    int lane = threadIdx.x & 63;
    int row = blockIdx.x * 4 + wid;
    if (row >= NN) return;
    int start = off[row];
    int d = deg[row];
    const int uo = lane * 4;
    ushort4 bv = *reinterpret_cast<const ushort4*>(zbf + (size_t)row * CH + uo);
    float ax = bf2f(bv.x), ay = bf2f(bv.y), az = bf2f(bv.z), aw = bf2f(bv.w);
    int e = 0;
    while (e < d) {
        int i0 = (e + 0 < d) ? elist[start + e + 0] : -1;
        int i1 = (e + 1 < d) ? elist[start + e + 1] : -1;
        int i2 = (e + 2 < d) ? elist[start + e + 2] : -1;
        int i3 = (e + 3 < d) ? elist[start + e + 3] : -1;
        int i4 = (e + 4 < d) ? elist[start + e + 4] : -1;
        int i5 = (e + 5 < d) ? elist[start + e + 5] : -1;
        int i6 = (e + 6 < d) ? elist[start + e + 6] : -1;
        int i7 = (e + 7 < d) ? elist[start + e + 7] : -1;
#define GACC(ii) if (ii >= 0) { \
            ushort4 v = *reinterpret_cast<const ushort4*>(zbf + (size_t)ii * CH + uo); \
            ax += bf2f(v.x); ay += bf2f(v.y); az += bf2f(v.z); aw += bf2f(v.w); }
        GACC(i0) GACC(i1) GACC(i2) GACC(i3) GACC(i4) GACC(i5) GACC(i6) GACC(i7)
#undef GACC
        e += 8;
    }
    const float nv = norm[row];
    float4 o;
    o.x = ax * nv; o.y = ay * nv; o.z = az * nv; o.w = aw * nv;
    *reinterpret_cast<float4*>(out + (size_t)row * CH + uo) = o;
}

// ---------------- Path B (fallback: fused f32 kernel) ----------------
__global__ __launch_bounds__(256, 4) void k_fgg(const float* __restrict__ x,
                                                const int* __restrict__ off,
                                                const int* __restrict__ deg,
                                                const int* __restrict__ elist,
                                                const float* __restrict__ norm,
                                                const unsigned short* __restrict__ Wt,
                                                float* __restrict__ out) {
    __shared__ unsigned short lds_a[64 * CH];
    const int tid = threadIdx.x;
    const int wid = tid >> 6;
    const int lane = tid & 63;
    const int rb = blockIdx.x * 64;
    const int rowbase = rb + wid * 16;
    const int r16 = lane & 15;
    const int q = lane >> 4;
    const int fo4 = lane * 4;

    const int offv = off[rowbase + r16];
    const int degv = deg[rowbase + r16];
    const float nv = norm[rb + lane];

    float4 acc[16];
#pragma unroll
    for (int r = 0; r < 16; ++r)
        acc[r] = *reinterpret_cast<const float4*>(x + (size_t)(rowbase + r) * CH + fo4);

#pragma unroll
    for (int r = 0; r < 16; ++r) {
        const int start = __shfl(offv, r);
        const int d = __shfl(degv, r);
        int e = 0;
        while (e < d) {
            int i0 = (e + 0 < d) ? elist[start + e + 0] : -1;
            int i1 = (e + 1 < d) ? elist[start + e + 1] : -1;
            int i2 = (e + 2 < d) ? elist[start + e + 2] : -1;
            int i3 = (e + 3 < d) ? elist[start + e + 3] : -1;
#define GACC(ii) if (ii >= 0) { \
            float4 v = *reinterpret_cast<const float4*>(x + (size_t)ii * CH + fo4); \
            acc[r].x += v.x; acc[r].y += v.y; acc[r].z += v.z; acc[r].w += v.w; }
            GACC(i0) GACC(i1) GACC(i2) GACC(i3)
#undef GACC
            e += 4;
        }
    }

    unsigned short* lb = lds_a + wid * 16 * CH;
#pragma unroll
    for (int r = 0; r < 16; ++r) {
        ushort4 w;
        w.x = f2bf(acc[r].x); w.y = f2bf(acc[r].y);
        w.z = f2bf(acc[r].z); w.w = f2bf(acc[r].w);
        const int gs = (lane >> 1) ^ (r & 7);
        *reinterpret_cast<ushort4*>(lb + r * CH + gs * 8 + (lane & 1) * 4) = w;
    }
    __syncthreads();

    f32x4 facc[4][4];
#pragma unroll
    for (int m = 0; m < 4; ++m)
#pragma unroll
        for (int nt = 0; nt < 4; ++nt) facc[m][nt] = (f32x4){0.f, 0.f, 0.f, 0.f};

    const unsigned short* wb = Wt + (size_t)(wid * 64 + r16) * CH + q * 8;

#pragma unroll
    for (int kk = 0; kk < 8; ++kk) {
        bf16x8 b[4];
#pragma unroll
        for (int nt = 0; nt < 4; ++nt)
            b[nt] = *reinterpret_cast<const bf16x8*>(wb + (size_t)nt * 16 * CH + kk * 32);
        bf16x8 a[4];
#pragma unroll
        for (int m = 0; m < 4; ++m) {
            const int lr = m * 16 + r16;
            const int idx = lr * CH + ((((kk * 4) + q) ^ (lr & 7)) << 3);
            a[m] = *reinterpret_cast<const bf16x8*>(&lds_a[idx]);
        }
#pragma unroll
        for (int m = 0; m < 4; ++m)
#pragma unroll
            for (int nt = 0; nt < 4; ++nt)
                facc[m][nt] = __builtin_amdgcn_mfma_f32_16x16x32_bf16(a[m], b[nt], facc[m][nt], 0, 0, 0);
    }

#pragma unroll
    for (int m = 0; m < 4; ++m) {
        const int crow = rb + m * 16 + q * 4;
#pragma unroll
        for (int nt = 0; nt < 4; ++nt) {
            float* po = out + (size_t)crow * CH + wid * 64 + nt * 16 + r16;
#pragma unroll
            for (int r = 0; r < 4; ++r) {
                const float nj = __shfl(nv, m * 16 + q * 4 + r);
                po[(size_t)r * CH] = facc[m][nt][r] * nj;
            }
        }
    }
}

extern "C" void kernel_launch(void* const* d_in, const int* in_sizes, int n_in,
                              void* d_out, int out_size, void* d_ws, size_t ws_size,
                              hipStream_t stream) {
    const float* x = (const float*)d_in[0];
    const int* se = (const int*)d_in[1];
    const int* te = (const int*)d_in[2];
    const float* norm = (const float*)d_in[3];
    const float* W = (const float*)d_in[4];
    float* out = (float*)d_out;

    char* ws = (char*)d_ws;
    unsigned short* Wt = (unsigned short*)ws;             // 128 KB
    int* deg   = (int*)(ws + 131072);                     // 800 KB
    int* off   = (int*)(ws + 931072);                     // 800 KB
    int* cur   = (int*)(ws + 1731072);                    // 800 KB
    int* elist = (int*)(ws + 2531072);                    // 2.4 MB
    int* bsum  = (int*)(ws + 4931072);                    // 1 KB
    const size_t ZBF_OFF = 4932096;
    const size_t NEED = ZBF_OFF + (size_t)NN * CH * 2;    // ~107.3 MB
    const bool big = (ws_size >= NEED);
    unsigned short* zbf = (unsigned short*)(ws + ZBF_OFF);

    hipMemsetAsync(deg, 0, NN * sizeof(int), stream);
    if (big) {
        k_wt<<<CH, CH, 0, stream>>>(W, Wt);
        k_zw<<<ZW_GRID, 256, 0, stream>>>(x, Wt, zbf, te, deg);
        k_scanA<<<NBLK_SCAN, 256, 0, stream>>>(deg, off, bsum);
        k_scanC<<<NBLK_SCAN, 256, 0, stream>>>(off, bsum, cur);
        k_fill<<<(NE + 255) / 256, 256, 0, stream>>>(se, te, cur, elist);
        k_gout<<<NN / 4, 256, 0, stream>>>(zbf, off, deg, elist, norm, out);
    } else {
        k_prep<<<512, 256, 0, stream>>>(W, Wt, te, deg);
        k_scanA<<<NBLK_SCAN, 256, 0, stream>>>(deg, off, bsum);
        k_scanC<<<NBLK_SCAN, 256, 0, stream>>>(off, bsum, cur);
        k_fill<<<(NE + 255) / 256, 256, 0, stream>>>(se, te, cur, elist);
        k_fgg<<<NN / 64, 256, 0, stream>>>(x, off, deg, elist, norm, Wt, out);
    }
}